// Round 2
// baseline (6147.109 us; speedup 1.0000x reference)
//
#include <hip/hip_runtime.h>

#define LEAKY 0.2f

__device__ __forceinline__ float bcast(float v, int k) {
  return __uint_as_float(__builtin_amdgcn_readlane(__float_as_uint(v), k));
}

__global__ __launch_bounds__(256) void k_zero_i32(int* __restrict__ p, int n) {
  int i = blockIdx.x * blockDim.x + threadIdx.x;
  if (i < n) p[i] = 0;
}

__global__ __launch_bounds__(256) void k_zero_f32(float* __restrict__ p, int n) {
  int i = blockIdx.x * blockDim.x + threadIdx.x;
  if (i < n) p[i] = 0.f;
}

__global__ __launch_bounds__(256) void k_hist(const int* __restrict__ rcv,
                                              int* __restrict__ deg, int n) {
  int i = blockIdx.x * blockDim.x + threadIdx.x;
  if (i < n) atomicAdd(&deg[rcv[i]], 1);
}

// inclusive scan, 256/block, Hillis-Steele in LDS
__global__ __launch_bounds__(256) void k_scan1(const int* __restrict__ deg,
                                               int* __restrict__ incl,
                                               int* __restrict__ bsum, int n) {
  __shared__ int sh[256];
  int i = blockIdx.x * 256 + threadIdx.x;
  int v = (i < n) ? deg[i] : 0;
  sh[threadIdx.x] = v;
  __syncthreads();
  for (int off = 1; off < 256; off <<= 1) {
    int t = (threadIdx.x >= (unsigned)off) ? sh[threadIdx.x - off] : 0;
    __syncthreads();
    sh[threadIdx.x] += t;
    __syncthreads();
  }
  if (i < n) incl[i] = sh[threadIdx.x];
  if (threadIdx.x == 255) bsum[blockIdx.x] = sh[255];
}

// scan the (<=512) block sums in a single block
__global__ __launch_bounds__(512) void k_scan2(int* __restrict__ bsum, int nb) {
  __shared__ int sh[512];
  int v = ((int)threadIdx.x < nb) ? bsum[threadIdx.x] : 0;
  sh[threadIdx.x] = v;
  __syncthreads();
  for (int off = 1; off < 512; off <<= 1) {
    int t = (threadIdx.x >= (unsigned)off) ? sh[threadIdx.x - off] : 0;
    __syncthreads();
    sh[threadIdx.x] += t;
    __syncthreads();
  }
  if ((int)threadIdx.x < nb) bsum[threadIdx.x] = sh[threadIdx.x];
}

__global__ __launch_bounds__(256) void k_scan3(int* __restrict__ incl,
                                               const int* __restrict__ bsum,
                                               const int* __restrict__ deg,
                                               int* __restrict__ cursor, int n) {
  int i = blockIdx.x * 256 + threadIdx.x;
  if (i >= n) return;
  int add = (blockIdx.x > 0) ? bsum[blockIdx.x - 1] : 0;
  int inc = incl[i] + add;
  incl[i] = inc;
  cursor[i] = inc - deg[i];
}

// scatter edge ids (and pre-gathered sender ids) into receiver-sorted order
__global__ __launch_bounds__(256) void k_scatter(const int* __restrict__ rcv,
                                                 const int* __restrict__ snd,
                                                 int* __restrict__ cursor,
                                                 int2* __restrict__ epair, int n) {
  int i = blockIdx.x * blockDim.x + threadIdx.x;
  if (i < n) {
    int pos = atomicAdd(&cursor[rcv[i]], 1);
    epair[pos] = make_int2(i, snd[i]);
  }
}

// q = h @ Wq ; kn = h @ Wk    (wave per node, lane = output feature)
__global__ __launch_bounds__(256) void k_node(const float* __restrict__ h,
                                              const float* __restrict__ Wq,
                                              const float* __restrict__ Wk,
                                              float* __restrict__ q,
                                              float* __restrict__ kn, int N) {
  int lane = threadIdx.x & 63;
  int wid = (blockIdx.x * blockDim.x + threadIdx.x) >> 6;
  int nw = (gridDim.x * blockDim.x) >> 6;
  float wq[64], wk[64];
#pragma unroll
  for (int k = 0; k < 64; k++) {
    wq[k] = Wq[k * 64 + lane];
    wk[k] = Wk[k * 64 + lane];
  }
  for (int n = wid; n < N; n += nw) {
    float hv = h[(size_t)n * 64 + lane];
    // 4 independent FMA chains (2 outputs x 2) to beat dependent-FMA latency
    float aq0 = 0.f, aq1 = 0.f, ak0 = 0.f, ak1 = 0.f;
#pragma unroll
    for (int k = 0; k < 64; k += 2) {
      float x0 = bcast(hv, k);
      float x1 = bcast(hv, k + 1);
      aq0 = fmaf(x0, wq[k], aq0);
      ak0 = fmaf(x0, wk[k], ak0);
      aq1 = fmaf(x1, wq[k + 1], aq1);
      ak1 = fmaf(x1, wk[k + 1], ak1);
    }
    q[(size_t)n * 64 + lane] = aq0 + aq1;
    kn[(size_t)n * 64 + lane] = ak0 + ak1;
  }
}

// Fused GATv2 hop, receiver-centric: wave per node, lane = feature.
// Online softmax (deferred-max, THR=8) over incoming edges; v stays in regs.
__global__ __launch_bounds__(256) void k_edge(
    const float* __restrict__ efeat, const float* __restrict__ q,
    const float* __restrict__ kn, const float* __restrict__ We,
    const float* __restrict__ b, const float* __restrict__ att,
    const int* __restrict__ incl, const int* __restrict__ deg,
    const int2* __restrict__ epair, float* __restrict__ hout, int N) {
  int lane = threadIdx.x & 63;
  int wid = (blockIdx.x * blockDim.x + threadIdx.x) >> 6;
  int nw = (gridDim.x * blockDim.x) >> 6;
  // We column for this lane lives in 64 VGPRs (static indices only)
  float wcol[64];
#pragma unroll
  for (int k = 0; k < 64; k++) wcol[k] = We[k * 64 + lane];
  float bl = b[lane], al = att[lane];
  for (int n = wid; n < N; n += nw) {
    int end = incl[n];
    int d = deg[n];
    int start = end - d;
    float outv = 0.f;
    if (d > 0) {  // wave-uniform branch; also guards pipelined prologue OOB
      float qb = q[(size_t)n * 64 + lane] + bl;
      float m = -3.0e38f, s = 0.f, acc = 0.f;
      // 1-deep software pipeline: rows for edge p+1 load under edge p's FMAs
      int2 es = epair[start];
      float ev = efeat[(size_t)es.x * 64 + lane];
      float knv = kn[(size_t)es.y * 64 + lane];
      for (int p = start; p < end; ++p) {
        int pn = (p + 1 < end) ? (p + 1) : p;  // branchless clamp
        int2 es_n = epair[pn];
        float ev_n = efeat[(size_t)es_n.x * 64 + lane];
        float knv_n = kn[(size_t)es_n.y * 64 + lane];
        // ke = (e row) @ We column, 4 independent chains
        float ke0 = 0.f, ke1 = 0.f, ke2 = 0.f, ke3 = 0.f;
#pragma unroll
        for (int k = 0; k < 64; k += 4) {
          ke0 = fmaf(bcast(ev, k), wcol[k], ke0);
          ke1 = fmaf(bcast(ev, k + 1), wcol[k + 1], ke1);
          ke2 = fmaf(bcast(ev, k + 2), wcol[k + 2], ke2);
          ke3 = fmaf(bcast(ev, k + 3), wcol[k + 3], ke3);
        }
        float v = knv + (ke0 + ke1) + (ke2 + ke3);
        float feat = qb + v;
        float act = feat >= 0.f ? feat : LEAKY * feat;
        float t = act * al;
#pragma unroll
        for (int o = 1; o < 64; o <<= 1) t += __shfl_xor(t, o);  // dot all-reduce
        // deferred-max online softmax; t wave-uniform, branch wave-uniform
        if (t > m + 8.f) {  // rare rescale; p values bounded by e^8 otherwise
          float sc = __expf(m - t);
          s *= sc;
          acc *= sc;
          m = t;
        }
        float pexp = __expf(t - m);
        s += pexp;
        acc = fmaf(pexp, v, acc);
        ev = ev_n;
        knv = knv_n;
      }
      outv = acc / s;
    }
    hout[(size_t)n * 64 + lane] = outv > 0.f ? outv : 0.f;  // relu
  }
}

__global__ __launch_bounds__(256) void k_mean(const float* __restrict__ h,
                                              float* __restrict__ out, int N) {
  int lane = threadIdx.x & 63;
  int row0 = (blockIdx.x * blockDim.x + threadIdx.x) >> 6;
  int stride = (gridDim.x * blockDim.x) >> 6;
  float s = 0.f;
  for (int n = row0; n < N; n += stride) s += h[(size_t)n * 64 + lane];
  __shared__ float sh[256];
  sh[threadIdx.x] = s;
  __syncthreads();
  if (threadIdx.x < 64) {
    float t = sh[threadIdx.x] + sh[64 + threadIdx.x] + sh[128 + threadIdx.x] +
              sh[192 + threadIdx.x];
    atomicAdd(&out[threadIdx.x], t * (1.0f / (float)N));
  }
}

extern "C" void kernel_launch(void* const* d_in, const int* in_sizes, int n_in,
                              void* d_out, int out_size, void* d_ws, size_t ws_size,
                              hipStream_t stream) {
  const float* node_feats = (const float*)d_in[0];
  const float* edge_feats = (const float*)d_in[1];
  const int* senders = (const int*)d_in[2];
  const int* receivers = (const int*)d_in[3];
  const float* Wq = (const float*)d_in[4];
  const float* Wk = (const float*)d_in[5];
  const float* We = (const float*)d_in[6];
  const float* bb = (const float*)d_in[7];
  const float* att = (const float*)d_in[8];
  float* out = (float*)d_out;
  const int N = in_sizes[0] / 64;
  const int E = in_sizes[2];

  // carve workspace (~116 MB)
  char* w = (char*)d_ws;
  auto alloc = [&](size_t bytes) {
    void* p = (void*)w;
    w += (bytes + 255) & ~(size_t)255;
    return p;
  };
  float* q = (float*)alloc((size_t)N * 64 * 4);
  float* kn = (float*)alloc((size_t)N * 64 * 4);
  float* hA = (float*)alloc((size_t)N * 64 * 4);
  float* hB = (float*)alloc((size_t)N * 64 * 4);
  int* deg = (int*)alloc((size_t)N * 4);
  int* incl = (int*)alloc((size_t)N * 4);
  int* cursor = (int*)alloc((size_t)N * 4);
  int* bsum = (int*)alloc(512 * 4);
  int2* epair = (int2*)alloc((size_t)E * 8);

  int nbN = (N + 255) / 256;
  int nbE = (E + 255) / 256;

  // CSR build (receivers fixed per call; rebuilt every call — no state carried)
  k_zero_i32<<<nbN, 256, 0, stream>>>(deg, N);
  k_hist<<<nbE, 256, 0, stream>>>(receivers, deg, E);
  k_scan1<<<nbN, 256, 0, stream>>>(deg, incl, bsum, N);
  k_scan2<<<1, 512, 0, stream>>>(bsum, nbN);
  k_scan3<<<nbN, 256, 0, stream>>>(incl, bsum, deg, cursor, N);
  k_scatter<<<nbE, 256, 0, stream>>>(receivers, senders, cursor, epair, E);

  const float* hin = node_feats;
  float* hout = hA;
  for (int i = 0; i < 8; i++) {
    k_node<<<2048, 256, 0, stream>>>(hin, Wq + (size_t)i * 4096,
                                     Wk + (size_t)i * 4096, q, kn, N);
    k_edge<<<2048, 256, 0, stream>>>(edge_feats, q, kn, We + (size_t)i * 4096,
                                     bb + (size_t)i * 64, att + (size_t)i * 64,
                                     incl, deg, epair, hout, N);
    hin = hout;
    hout = (hout == hA) ? hB : hA;
  }

  k_zero_f32<<<1, 64, 0, stream>>>(out, 64);
  k_mean<<<256, 256, 0, stream>>>(hin, out, N);
}

// Round 5
// 5961.006 us; speedup vs baseline: 1.0312x; 1.0312x over previous
//
#include <hip/hip_runtime.h>

#define LEAKY 0.2f

__device__ __forceinline__ int rfl(int v) { return __builtin_amdgcn_readfirstlane(v); }

__global__ __launch_bounds__(256) void k_zero_i32(int* __restrict__ p, int n) {
  int i = blockIdx.x * blockDim.x + threadIdx.x;
  if (i < n) p[i] = 0;
}

__global__ __launch_bounds__(256) void k_zero_f32(float* __restrict__ p, int n) {
  int i = blockIdx.x * blockDim.x + threadIdx.x;
  if (i < n) p[i] = 0.f;
}

__global__ __launch_bounds__(256) void k_hist(const int* __restrict__ rcv,
                                              int* __restrict__ deg, int n) {
  int i = blockIdx.x * blockDim.x + threadIdx.x;
  if (i < n) atomicAdd(&deg[rcv[i]], 1);
}

// inclusive scan, 256/block, Hillis-Steele in LDS
__global__ __launch_bounds__(256) void k_scan1(const int* __restrict__ deg,
                                               int* __restrict__ incl,
                                               int* __restrict__ bsum, int n) {
  __shared__ int sh[256];
  int i = blockIdx.x * 256 + threadIdx.x;
  int v = (i < n) ? deg[i] : 0;
  sh[threadIdx.x] = v;
  __syncthreads();
  for (int off = 1; off < 256; off <<= 1) {
    int t = (threadIdx.x >= (unsigned)off) ? sh[threadIdx.x - off] : 0;
    __syncthreads();
    sh[threadIdx.x] += t;
    __syncthreads();
  }
  if (i < n) incl[i] = sh[threadIdx.x];
  if (threadIdx.x == 255) bsum[blockIdx.x] = sh[255];
}

__global__ __launch_bounds__(512) void k_scan2(int* __restrict__ bsum, int nb) {
  __shared__ int sh[512];
  int v = ((int)threadIdx.x < nb) ? bsum[threadIdx.x] : 0;
  sh[threadIdx.x] = v;
  __syncthreads();
  for (int off = 1; off < 512; off <<= 1) {
    int t = (threadIdx.x >= (unsigned)off) ? sh[threadIdx.x - off] : 0;
    __syncthreads();
    sh[threadIdx.x] += t;
    __syncthreads();
  }
  if ((int)threadIdx.x < nb) bsum[threadIdx.x] = sh[threadIdx.x];
}

__global__ __launch_bounds__(256) void k_scan3(int* __restrict__ incl,
                                               const int* __restrict__ bsum,
                                               const int* __restrict__ deg,
                                               int* __restrict__ cursor, int n) {
  int i = blockIdx.x * 256 + threadIdx.x;
  if (i >= n) return;
  int add = (blockIdx.x > 0) ? bsum[blockIdx.x - 1] : 0;
  int inc = incl[i] + add;
  incl[i] = inc;
  cursor[i] = inc - deg[i];
}

__global__ __launch_bounds__(256) void k_scatter(const int* __restrict__ rcv,
                                                 const int* __restrict__ snd,
                                                 int* __restrict__ cursor,
                                                 int2* __restrict__ epair, int n) {
  int i = blockIdx.x * blockDim.x + threadIdx.x;
  if (i < n) {
    int pos = atomicAdd(&cursor[rcv[i]], 1);
    epair[pos] = make_int2(i, snd[i]);
  }
}

// q = h @ Wq ; kn = h @ Wk    (wave per node, lane = output feature)
// h row is wave-uniform -> s_load into SGPRs; Wq/Wk columns pinned in VGPRs.
__global__ __launch_bounds__(256) void k_node(const float* __restrict__ h,
                                              const float* __restrict__ Wq,
                                              const float* __restrict__ Wk,
                                              float* __restrict__ q,
                                              float* __restrict__ kn, int N) {
  int lane = threadIdx.x & 63;
  int wid = (blockIdx.x * blockDim.x + threadIdx.x) >> 6;
  int nw = (gridDim.x * blockDim.x) >> 6;
  float wq[64], wk[64];
#pragma unroll
  for (int k = 0; k < 64; k++) {
    wq[k] = Wq[k * 64 + lane];
    wk[k] = Wk[k * 64 + lane];
    asm volatile("" : "+v"(wq[k]));  // pin in VGPR: forbid re-load inside loop
    asm volatile("" : "+v"(wk[k]));
  }
  for (int n0 = wid; n0 < N; n0 += nw) {
    int n = rfl(n0);  // force wave-uniform -> scalar loads below
    const float* hr = h + (size_t)n * 64;  // uniform row base
    float aq0 = 0.f, aq1 = 0.f, ak0 = 0.f, ak1 = 0.f;
#pragma unroll
    for (int k = 0; k < 64; k += 2) {
      float x0 = hr[k];      // uniform load -> SGPR operand
      float x1 = hr[k + 1];
      aq0 = fmaf(x0, wq[k], aq0);
      ak0 = fmaf(x0, wk[k], ak0);
      aq1 = fmaf(x1, wq[k + 1], aq1);
      ak1 = fmaf(x1, wk[k + 1], ak1);
    }
    q[(size_t)n * 64 + lane] = aq0 + aq1;
    kn[(size_t)n * 64 + lane] = ak0 + ak1;
  }
}

// Fused GATv2 hop, receiver-centric: wave per node, lane = feature.
// e-row via scalar loads (wave-uniform addr, rfl-forced), We column pinned in
// VGPRs, online softmax (deferred-max THR=8); v stays in registers.
__global__ __launch_bounds__(256) void k_edge(
    const float* __restrict__ efeat, const float* __restrict__ q,
    const float* __restrict__ kn, const float* __restrict__ We,
    const float* __restrict__ b, const float* __restrict__ att,
    const int* __restrict__ incl, const int* __restrict__ deg,
    const int2* __restrict__ epair, float* __restrict__ hout, int N) {
  int lane = threadIdx.x & 63;
  int wid = (blockIdx.x * blockDim.x + threadIdx.x) >> 6;
  int nw = (gridDim.x * blockDim.x) >> 6;
  float wcol[64];
#pragma unroll
  for (int k = 0; k < 64; k++) {
    wcol[k] = We[k * 64 + lane];
    asm volatile("" : "+v"(wcol[k]));  // pin in VGPR
  }
  float bl = b[lane], al = att[lane];
  for (int n0 = wid; n0 < N; n0 += nw) {
    int n = rfl(n0);  // wave-uniform node
    int end = incl[n];   // uniform -> s_load
    int d = deg[n];      // uniform -> s_load
    int start = end - d;
    float outv = 0.f;
    if (d > 0) {  // wave-uniform; also guards prologue OOB
      float qb = q[(size_t)n * 64 + lane] + bl;
      float m = -3.0e38f, s = 0.f, acc = 0.f;
      // 1-deep prefetch of the kn row; e-row goes via SMEM each iter
      int2 es = epair[start];
      float knv = kn[(size_t)es.y * 64 + lane];
      for (int p = start; p < end; ++p) {
        int pn = (p + 1 < end) ? (p + 1) : p;
        int2 es_n = epair[pn];
        float knv_n = kn[(size_t)es_n.y * 64 + lane];  // vector prefetch
        // rfl forces the row base into SGPRs even if epair[p] lowered to VGPR
        const float* er = efeat + (size_t)rfl(es.x) * 64;
        float ke0 = 0.f, ke1 = 0.f, ke2 = 0.f, ke3 = 0.f;
#pragma unroll
        for (int k = 0; k < 64; k += 4) {   // v_fmac v, s, v — 1 SGPR read/op
          ke0 = fmaf(er[k], wcol[k], ke0);
          ke1 = fmaf(er[k + 1], wcol[k + 1], ke1);
          ke2 = fmaf(er[k + 2], wcol[k + 2], ke2);
          ke3 = fmaf(er[k + 3], wcol[k + 3], ke3);
        }
        float v = knv + (ke0 + ke1) + (ke2 + ke3);
        float feat = qb + v;
        float act = feat >= 0.f ? feat : LEAKY * feat;
        float t = act * al;
#pragma unroll
        for (int o = 1; o < 64; o <<= 1) t += __shfl_xor(t, o);  // logit reduce
        if (t > m + 8.f) {  // deferred-max rescale (rare, wave-uniform)
          float sc = __expf(m - t);
          s *= sc;
          acc *= sc;
          m = t;
        }
        float pexp = __expf(t - m);
        s += pexp;
        acc = fmaf(pexp, v, acc);
        es = es_n;
        knv = knv_n;
      }
      outv = acc / s;
    }
    hout[(size_t)n * 64 + lane] = outv > 0.f ? outv : 0.f;  // relu
  }
}

__global__ __launch_bounds__(256) void k_mean(const float* __restrict__ h,
                                              float* __restrict__ out, int N) {
  int lane = threadIdx.x & 63;
  int row0 = (blockIdx.x * blockDim.x + threadIdx.x) >> 6;
  int stride = (gridDim.x * blockDim.x) >> 6;
  float s = 0.f;
  for (int n = row0; n < N; n += stride) s += h[(size_t)n * 64 + lane];
  __shared__ float sh[256];
  sh[threadIdx.x] = s;
  __syncthreads();
  if (threadIdx.x < 64) {
    float t = sh[threadIdx.x] + sh[64 + threadIdx.x] + sh[128 + threadIdx.x] +
              sh[192 + threadIdx.x];
    atomicAdd(&out[threadIdx.x], t * (1.0f / (float)N));
  }
}

extern "C" void kernel_launch(void* const* d_in, const int* in_sizes, int n_in,
                              void* d_out, int out_size, void* d_ws, size_t ws_size,
                              hipStream_t stream) {
  const float* node_feats = (const float*)d_in[0];
  const float* edge_feats = (const float*)d_in[1];
  const int* senders = (const int*)d_in[2];
  const int* receivers = (const int*)d_in[3];
  const float* Wq = (const float*)d_in[4];
  const float* Wk = (const float*)d_in[5];
  const float* We = (const float*)d_in[6];
  const float* bb = (const float*)d_in[7];
  const float* att = (const float*)d_in[8];
  float* out = (float*)d_out;
  const int N = in_sizes[0] / 64;
  const int E = in_sizes[2];

  char* w = (char*)d_ws;
  auto alloc = [&](size_t bytes) {
    void* p = (void*)w;
    w += (bytes + 255) & ~(size_t)255;
    return p;
  };
  float* q = (float*)alloc((size_t)N * 64 * 4);
  float* kn = (float*)alloc((size_t)N * 64 * 4);
  float* hA = (float*)alloc((size_t)N * 64 * 4);
  float* hB = (float*)alloc((size_t)N * 64 * 4);
  int* deg = (int*)alloc((size_t)N * 4);
  int* incl = (int*)alloc((size_t)N * 4);
  int* cursor = (int*)alloc((size_t)N * 4);
  int* bsum = (int*)alloc(512 * 4);
  int2* epair = (int2*)alloc((size_t)E * 8);

  int nbN = (N + 255) / 256;
  int nbE = (E + 255) / 256;

  // CSR build (rebuilt every call — no cross-call state)
  k_zero_i32<<<nbN, 256, 0, stream>>>(deg, N);
  k_hist<<<nbE, 256, 0, stream>>>(receivers, deg, E);
  k_scan1<<<nbN, 256, 0, stream>>>(deg, incl, bsum, N);
  k_scan2<<<1, 512, 0, stream>>>(bsum, nbN);
  k_scan3<<<nbN, 256, 0, stream>>>(incl, bsum, deg, cursor, N);
  k_scatter<<<nbE, 256, 0, stream>>>(receivers, senders, cursor, epair, E);

  const float* hin = node_feats;
  float* hout = hA;
  for (int i = 0; i < 8; i++) {
    k_node<<<2048, 256, 0, stream>>>(hin, Wq + (size_t)i * 4096,
                                     Wk + (size_t)i * 4096, q, kn, N);
    k_edge<<<4096, 256, 0, stream>>>(edge_feats, q, kn, We + (size_t)i * 4096,
                                     bb + (size_t)i * 64, att + (size_t)i * 64,
                                     incl, deg, epair, hout, N);
    hin = hout;
    hout = (hout == hA) ? hB : hA;
  }

  k_zero_f32<<<1, 64, 0, stream>>>(out, 64);
  k_mean<<<256, 256, 0, stream>>>(hin, out, N);
}

// Round 7
// 4870.558 us; speedup vs baseline: 1.2621x; 1.2239x over previous
//
#include <hip/hip_runtime.h>

#define LEAKY 0.2f

__global__ __launch_bounds__(256) void k_zero_i32(int* __restrict__ p, int n) {
  int i = blockIdx.x * blockDim.x + threadIdx.x;
  if (i < n) p[i] = 0;
}

__global__ __launch_bounds__(256) void k_zero_f32(float* __restrict__ p, int n) {
  int i = blockIdx.x * blockDim.x + threadIdx.x;
  if (i < n) p[i] = 0.f;
}

__global__ __launch_bounds__(256) void k_hist(const int* __restrict__ rcv,
                                              int* __restrict__ deg, int n) {
  int i = blockIdx.x * blockDim.x + threadIdx.x;
  if (i < n) atomicAdd(&deg[rcv[i]], 1);
}

// inclusive scan, 256/block, Hillis-Steele in LDS
__global__ __launch_bounds__(256) void k_scan1(const int* __restrict__ deg,
                                               int* __restrict__ incl,
                                               int* __restrict__ bsum, int n) {
  __shared__ int sh[256];
  int i = blockIdx.x * 256 + threadIdx.x;
  int v = (i < n) ? deg[i] : 0;
  sh[threadIdx.x] = v;
  __syncthreads();
  for (int off = 1; off < 256; off <<= 1) {
    int t = (threadIdx.x >= (unsigned)off) ? sh[threadIdx.x - off] : 0;
    __syncthreads();
    sh[threadIdx.x] += t;
    __syncthreads();
  }
  if (i < n) incl[i] = sh[threadIdx.x];
  if (threadIdx.x == 255) bsum[blockIdx.x] = sh[255];
}

__global__ __launch_bounds__(512) void k_scan2(int* __restrict__ bsum, int nb) {
  __shared__ int sh[512];
  int v = ((int)threadIdx.x < nb) ? bsum[threadIdx.x] : 0;
  sh[threadIdx.x] = v;
  __syncthreads();
  for (int off = 1; off < 512; off <<= 1) {
    int t = (threadIdx.x >= (unsigned)off) ? sh[threadIdx.x - off] : 0;
    __syncthreads();
    sh[threadIdx.x] += t;
    __syncthreads();
  }
  if ((int)threadIdx.x < nb) bsum[threadIdx.x] = sh[threadIdx.x];
}

__global__ __launch_bounds__(256) void k_scan3(int* __restrict__ incl,
                                               const int* __restrict__ bsum,
                                               const int* __restrict__ deg,
                                               int* __restrict__ cursor, int n) {
  int i = blockIdx.x * 256 + threadIdx.x;
  if (i >= n) return;
  int add = (blockIdx.x > 0) ? bsum[blockIdx.x - 1] : 0;
  int inc = incl[i] + add;
  incl[i] = inc;
  cursor[i] = inc - deg[i];
}

__global__ __launch_bounds__(256) void k_scatter(const int* __restrict__ rcv,
                                                 const int* __restrict__ snd,
                                                 int* __restrict__ cursor,
                                                 int2* __restrict__ epair, int n) {
  int i = blockIdx.x * blockDim.x + threadIdx.x;
  if (i < n) {
    int pos = atomicAdd(&cursor[rcv[i]], 1);
    epair[pos] = make_int2(i, snd[i]);
  }
}

// Dual tiled GEMM: Cq = A @ Bq, Ck = A @ Bk (A: M x 64, B: 64 x 64).
// 64x64 tile, 256 threads, A staged transposed+padded once for both outputs.
__global__ __launch_bounds__(256) void k_node2(
    const float* __restrict__ A, const float* __restrict__ Bq,
    const float* __restrict__ Bk, float* __restrict__ Cq,
    float* __restrict__ Ck, int M) {
  __shared__ float Bqs[64 * 64];
  __shared__ float Bks[64 * 64];
  __shared__ float At[64 * 68];
  int tid = threadIdx.x;
  {
    const float4* q4 = (const float4*)Bq;
    const float4* k4 = (const float4*)Bk;
    float4* s1 = (float4*)Bqs;
    float4* s2 = (float4*)Bks;
#pragma unroll
    for (int i = 0; i < 4; i++) {
      s1[tid + i * 256] = q4[tid + i * 256];
      s2[tid + i * 256] = k4[tid + i * 256];
    }
  }
  __syncthreads();
  int r0 = (tid >> 4) * 4;
  int c0 = (tid & 15) * 4;
  int ntiles = (M + 63) >> 6;
  for (int t = blockIdx.x; t < ntiles; t += gridDim.x) {
    int base = t << 6;
#pragma unroll
    for (int i = 0; i < 4; i++) {
      int row = (tid >> 4) + i * 16;
      int col = (tid & 15) * 4;
      int r = base + row;
      float4 v = make_float4(0.f, 0.f, 0.f, 0.f);
      if (r < M) v = *(const float4*)&A[(size_t)r * 64 + col];
      At[(col + 0) * 68 + row] = v.x;
      At[(col + 1) * 68 + row] = v.y;
      At[(col + 2) * 68 + row] = v.z;
      At[(col + 3) * 68 + row] = v.w;
    }
    __syncthreads();
    float aq[4][4], ak[4][4];
#pragma unroll
    for (int i = 0; i < 4; i++)
#pragma unroll
      for (int j = 0; j < 4; j++) {
        aq[i][j] = 0.f;
        ak[i][j] = 0.f;
      }
#pragma unroll 4
    for (int k = 0; k < 64; k++) {
      float4 a4 = *(const float4*)&At[k * 68 + r0];
      float4 bq = *(const float4*)&Bqs[k * 64 + c0];
      float4 bk = *(const float4*)&Bks[k * 64 + c0];
      aq[0][0] = fmaf(a4.x, bq.x, aq[0][0]); aq[0][1] = fmaf(a4.x, bq.y, aq[0][1]);
      aq[0][2] = fmaf(a4.x, bq.z, aq[0][2]); aq[0][3] = fmaf(a4.x, bq.w, aq[0][3]);
      aq[1][0] = fmaf(a4.y, bq.x, aq[1][0]); aq[1][1] = fmaf(a4.y, bq.y, aq[1][1]);
      aq[1][2] = fmaf(a4.y, bq.z, aq[1][2]); aq[1][3] = fmaf(a4.y, bq.w, aq[1][3]);
      aq[2][0] = fmaf(a4.z, bq.x, aq[2][0]); aq[2][1] = fmaf(a4.z, bq.y, aq[2][1]);
      aq[2][2] = fmaf(a4.z, bq.z, aq[2][2]); aq[2][3] = fmaf(a4.z, bq.w, aq[2][3]);
      aq[3][0] = fmaf(a4.w, bq.x, aq[3][0]); aq[3][1] = fmaf(a4.w, bq.y, aq[3][1]);
      aq[3][2] = fmaf(a4.w, bq.z, aq[3][2]); aq[3][3] = fmaf(a4.w, bq.w, aq[3][3]);
      ak[0][0] = fmaf(a4.x, bk.x, ak[0][0]); ak[0][1] = fmaf(a4.x, bk.y, ak[0][1]);
      ak[0][2] = fmaf(a4.x, bk.z, ak[0][2]); ak[0][3] = fmaf(a4.x, bk.w, ak[0][3]);
      ak[1][0] = fmaf(a4.y, bk.x, ak[1][0]); ak[1][1] = fmaf(a4.y, bk.y, ak[1][1]);
      ak[1][2] = fmaf(a4.y, bk.z, ak[1][2]); ak[1][3] = fmaf(a4.y, bk.w, ak[1][3]);
      ak[2][0] = fmaf(a4.z, bk.x, ak[2][0]); ak[2][1] = fmaf(a4.z, bk.y, ak[2][1]);
      ak[2][2] = fmaf(a4.z, bk.z, ak[2][2]); ak[2][3] = fmaf(a4.z, bk.w, ak[2][3]);
      ak[3][0] = fmaf(a4.w, bk.x, ak[3][0]); ak[3][1] = fmaf(a4.w, bk.y, ak[3][1]);
      ak[3][2] = fmaf(a4.w, bk.z, ak[3][2]); ak[3][3] = fmaf(a4.w, bk.w, ak[3][3]);
    }
    __syncthreads();
#pragma unroll
    for (int i = 0; i < 4; i++) {
      int r = base + r0 + i;
      if (r < M) {
        *(float4*)&Cq[(size_t)r * 64 + c0] =
            make_float4(aq[i][0], aq[i][1], aq[i][2], aq[i][3]);
        *(float4*)&Ck[(size_t)r * 64 + c0] =
            make_float4(ak[i][0], ak[i][1], ak[i][2], ak[i][3]);
      }
    }
  }
}

// Gather-GEMM: C[r] = efeat[epair[e0+r].x] @ B for the chunk's edges.
// Tile 64x64, 256 threads, 16 acc/thread, A staged transposed+padded.
__global__ __launch_bounds__(256) void k_gemmg(
    const float* __restrict__ A, const float* __restrict__ B,
    float* __restrict__ C, const int2* __restrict__ epair,
    const int* __restrict__ incl, int nlo, int nhi) {
  __shared__ float Bs[64 * 64];
  __shared__ float At[64 * 68];
  int tid = threadIdx.x;
  {
    const float4* B4 = (const float4*)B;
    float4* Bs4 = (float4*)Bs;
#pragma unroll
    for (int i = 0; i < 4; i++) Bs4[tid + i * 256] = B4[tid + i * 256];
  }
  int e0 = (nlo > 0) ? incl[nlo - 1] : 0;
  int rows = incl[nhi - 1] - e0;
  __syncthreads();
  int r0 = (tid >> 4) * 4;
  int c0 = (tid & 15) * 4;
  int ntiles = (rows + 63) >> 6;
  for (int t = blockIdx.x; t < ntiles; t += gridDim.x) {
    int base = t << 6;
#pragma unroll
    for (int i = 0; i < 4; i++) {
      int row = (tid >> 4) + i * 16;
      int col = (tid & 15) * 4;
      int r = base + row;
      float4 v = make_float4(0.f, 0.f, 0.f, 0.f);
      if (r < rows) {
        size_t arow = (size_t)epair[e0 + r].x;
        v = *(const float4*)&A[arow * 64 + col];
      }
      At[(col + 0) * 68 + row] = v.x;
      At[(col + 1) * 68 + row] = v.y;
      At[(col + 2) * 68 + row] = v.z;
      At[(col + 3) * 68 + row] = v.w;
    }
    __syncthreads();
    float acc[4][4];
#pragma unroll
    for (int i = 0; i < 4; i++)
#pragma unroll
      for (int j = 0; j < 4; j++) acc[i][j] = 0.f;
#pragma unroll 8
    for (int k = 0; k < 64; k++) {
      float4 a4 = *(const float4*)&At[k * 68 + r0];
      float4 b4 = *(const float4*)&Bs[k * 64 + c0];
      acc[0][0] = fmaf(a4.x, b4.x, acc[0][0]); acc[0][1] = fmaf(a4.x, b4.y, acc[0][1]);
      acc[0][2] = fmaf(a4.x, b4.z, acc[0][2]); acc[0][3] = fmaf(a4.x, b4.w, acc[0][3]);
      acc[1][0] = fmaf(a4.y, b4.x, acc[1][0]); acc[1][1] = fmaf(a4.y, b4.y, acc[1][1]);
      acc[1][2] = fmaf(a4.y, b4.z, acc[1][2]); acc[1][3] = fmaf(a4.y, b4.w, acc[1][3]);
      acc[2][0] = fmaf(a4.z, b4.x, acc[2][0]); acc[2][1] = fmaf(a4.z, b4.y, acc[2][1]);
      acc[2][2] = fmaf(a4.z, b4.z, acc[2][2]); acc[2][3] = fmaf(a4.z, b4.w, acc[2][3]);
      acc[3][0] = fmaf(a4.w, b4.x, acc[3][0]); acc[3][1] = fmaf(a4.w, b4.y, acc[3][1]);
      acc[3][2] = fmaf(a4.w, b4.z, acc[3][2]); acc[3][3] = fmaf(a4.w, b4.w, acc[3][3]);
    }
    __syncthreads();
#pragma unroll
    for (int i = 0; i < 4; i++) {
      int r = base + r0 + i;
      if (r < rows)
        *(float4*)&C[(size_t)r * 64 + c0] =
            make_float4(acc[i][0], acc[i][1], acc[i][2], acc[i][3]);
    }
  }
}

// Light fused hop: wave per receiver node, lane = feature. kesort streamed
// (chunk-local), kn gathered, online softmax (deferred-max THR=8).
// qh is read (q) then overwritten (h_out) for the SAME node by the SAME wave.
__global__ __launch_bounds__(256) void k_edge(
    const float* __restrict__ kesort, float* __restrict__ qh,
    const float* __restrict__ kn, const float* __restrict__ b,
    const float* __restrict__ att, const int* __restrict__ incl,
    const int* __restrict__ deg, const int2* __restrict__ epair,
    int nlo, int nhi) {
  int lane = threadIdx.x & 63;
  int wid = (blockIdx.x * blockDim.x + threadIdx.x) >> 6;
  int nw = (gridDim.x * blockDim.x) >> 6;
  float bl = b[lane], al = att[lane];
  int e0 = (nlo > 0) ? incl[nlo - 1] : 0;

#define LOADE(KE, KV, POS)                                   \
  {                                                          \
    int pp_ = (POS);                                         \
    int2 es_ = epair[pp_];                                   \
    KE = kesort[(size_t)(pp_ - e0) * 64 + lane];             \
    KV = kn[(size_t)es_.y * 64 + lane];                      \
  }
#define PROC(KE, KV)                                         \
  {                                                          \
    float v_ = (KV) + (KE);                                  \
    float f_ = qb + v_;                                      \
    float a_ = f_ >= 0.f ? f_ : LEAKY * f_;                  \
    float t_ = a_ * al;                                      \
    t_ += __shfl_xor(t_, 1);                                 \
    t_ += __shfl_xor(t_, 2);                                 \
    t_ += __shfl_xor(t_, 4);                                 \
    t_ += __shfl_xor(t_, 8);                                 \
    t_ += __shfl_xor(t_, 16);                                \
    t_ += __shfl_xor(t_, 32);                                \
    if (t_ > m + 8.f) {                                      \
      float sc_ = __expf(m - t_);                            \
      s *= sc_;                                              \
      acc *= sc_;                                            \
      m = t_;                                                \
    }                                                        \
    float p_ = __expf(t_ - m);                               \
    s += p_;                                                 \
    acc = fmaf(p_, v_, acc);                                 \
  }

  for (int n = nlo + wid; n < nhi; n += nw) {
    int end = incl[n];
    int d = deg[n];
    int start = end - d;
    float outv = 0.f;
    if (d > 0) {
      float qb = qh[(size_t)n * 64 + lane] + bl;
      float m = -3.0e38f, s = 0.f, acc = 0.f;
      float ke0, kv0, ke1, kv1, ke2, kv2, ke3, kv3;
      int last = end - 1;
      LOADE(ke0, kv0, start);
      LOADE(ke1, kv1, min(start + 1, last));
      LOADE(ke2, kv2, min(start + 2, last));
      LOADE(ke3, kv3, min(start + 3, last));
      for (int p = start; p < end; p += 4) {
        float nk0, nv0, nk1, nv1, nk2, nv2, nk3, nv3;
        bool pf = (p + 4 < end);  // wave-uniform
        if (pf) {
          LOADE(nk0, nv0, p + 4);
          LOADE(nk1, nv1, min(p + 5, last));
          LOADE(nk2, nv2, min(p + 6, last));
          LOADE(nk3, nv3, min(p + 7, last));
        }
        PROC(ke0, kv0);
        if (p + 1 < end) PROC(ke1, kv1);
        if (p + 2 < end) PROC(ke2, kv2);
        if (p + 3 < end) PROC(ke3, kv3);
        if (pf) {
          ke0 = nk0; kv0 = nv0; ke1 = nk1; kv1 = nv1;
          ke2 = nk2; kv2 = nv2; ke3 = nk3; kv3 = nv3;
        }
      }
      outv = acc / s;
    }
    qh[(size_t)n * 64 + lane] = outv > 0.f ? outv : 0.f;  // relu; overwrite q
  }
#undef LOADE
#undef PROC
}

__global__ __launch_bounds__(256) void k_mean(const float* __restrict__ h,
                                              float* __restrict__ out, int N) {
  int lane = threadIdx.x & 63;
  int row0 = (blockIdx.x * blockDim.x + threadIdx.x) >> 6;
  int stride = (gridDim.x * blockDim.x) >> 6;
  float s = 0.f;
  for (int n = row0; n < N; n += stride) s += h[(size_t)n * 64 + lane];
  __shared__ float sh[256];
  sh[threadIdx.x] = s;
  __syncthreads();
  if (threadIdx.x < 64) {
    float t = sh[threadIdx.x] + sh[64 + threadIdx.x] + sh[128 + threadIdx.x] +
              sh[192 + threadIdx.x];
    atomicAdd(&out[threadIdx.x], t * (1.0f / (float)N));
  }
}

extern "C" void kernel_launch(void* const* d_in, const int* in_sizes, int n_in,
                              void* d_out, int out_size, void* d_ws, size_t ws_size,
                              hipStream_t stream) {
  const float* node_feats = (const float*)d_in[0];
  const float* edge_feats = (const float*)d_in[1];
  const int* senders = (const int*)d_in[2];
  const int* receivers = (const int*)d_in[3];
  const float* Wq = (const float*)d_in[4];
  const float* Wk = (const float*)d_in[5];
  const float* We = (const float*)d_in[6];
  const float* bb = (const float*)d_in[7];
  const float* att = (const float*)d_in[8];
  float* out = (float*)d_out;
  const int N = in_sizes[0] / 64;
  const int E = in_sizes[2];

  char* w = (char*)d_ws;
  size_t used = 0;
  auto alloc = [&](size_t bytes) {
    void* p = (void*)(w + used);
    used += (bytes + 255) & ~(size_t)255;
    return p;
  };
  // q aliases hout (ping-pong A/B); kn separate. 3 N*64 bufs instead of 4.
  float* bufA = (float*)alloc((size_t)N * 64 * 4);
  float* bufB = (float*)alloc((size_t)N * 64 * 4);
  float* kn = (float*)alloc((size_t)N * 64 * 4);
  int* deg = (int*)alloc((size_t)N * 4);
  int* incl = (int*)alloc((size_t)N * 4);
  int* cursor = (int*)alloc((size_t)N * 4);
  int* bsum = (int*)alloc(512 * 4);
  int2* epair = (int2*)alloc((size_t)E * 8);

  // kesort chunk buffer: smallest power-of-2 NCH whose chunk fits remaining ws
  size_t avail = (ws_size > used) ? (ws_size - used) : 0;
  size_t cap_edges = avail / 256;  // 64 floats per edge
  int NCH = 1;
  while (NCH < 256 && (size_t)(E / NCH) + 16384 > cap_edges) NCH <<= 1;
  size_t chunk_cap = (size_t)(E / NCH) + 16384;
  float* kesort = (float*)alloc(chunk_cap * 256);

  int nbN = (N + 255) / 256;
  int nbE = (E + 255) / 256;

  // CSR build (rebuilt every call — no cross-call state)
  k_zero_i32<<<nbN, 256, 0, stream>>>(deg, N);
  k_hist<<<nbE, 256, 0, stream>>>(receivers, deg, E);
  k_scan1<<<nbN, 256, 0, stream>>>(deg, incl, bsum, N);
  k_scan2<<<1, 512, 0, stream>>>(bsum, nbN);
  k_scan3<<<nbN, 256, 0, stream>>>(incl, bsum, deg, cursor, N);
  k_scatter<<<nbE, 256, 0, stream>>>(receivers, senders, cursor, epair, E);

  int gg = (int)((E / NCH) / 64 + 32);
  if (gg > 2048) gg = 2048;
  const float* hin = node_feats;
  float* cur = bufA;
  float* oth = bufB;
  for (int i = 0; i < 8; i++) {
    float* qh = cur;  // q written here, then overwritten with h_out
    k_node2<<<1600, 256, 0, stream>>>(hin, Wq + (size_t)i * 4096,
                                      Wk + (size_t)i * 4096, qh, kn, N);
    for (int c = 0; c < NCH; c++) {
      int nlo = (int)((long long)N * c / NCH);
      int nhi = (int)((long long)N * (c + 1) / NCH);
      int ge = (nhi - nlo + 3) / 4;
      if (ge > 1024) ge = 1024;
      if (ge < 64) ge = 64;
      k_gemmg<<<gg, 256, 0, stream>>>(edge_feats, We + (size_t)i * 4096,
                                      kesort, epair, incl, nlo, nhi);
      k_edge<<<ge, 256, 0, stream>>>(kesort, qh, kn, bb + (size_t)i * 64,
                                     att + (size_t)i * 64, incl, deg, epair,
                                     nlo, nhi);
    }
    hin = qh;
    cur = oth;
    oth = qh;
  }

  k_zero_f32<<<1, 64, 0, stream>>>(out, 64);
  k_mean<<<256, 256, 0, stream>>>(hin, out, N);
}